// Round 6
// baseline (435.371 us; speedup 1.0000x reference)
//
#include <hip/hip_runtime.h>

// MHABlock (f32 I/O): BN -> xn(bf16) -> fused {k,v} + q MFMA GEMMs (8-phase pipelined) ->
// focus(q,k) -> linear attention (kv via MFMA K^T·V; o via MFMA Q·kv with fused dwc) ->
// proj GEMM (f32 out).
//
// R6: true T4 depth. Keep R5's 8-phase micro-interleave; change BK 64->32 with ring-4
// LDS (same 128 KB), pair-packed rows (LDS row r = global rows r / r+128, phys slot =
// logical ^ (r&7), 2-way = conflict-free; layout proven in R2). Stage tile kt+3 during
// kt (issue-to-read = 6 phases ~900+cy, covers HBM); publish kt+1 with COUNTED
// vmcnt(8) (kt+2/kt+3 stay in flight; never 0 until epilogue peels 8/4/0). R5 drained
// vmcnt(0) ~3 phases after issue -> publish stalled on slow loads; m218: counted-vs-
// drain0 within 8-phase is the dominant term. glds/ds_read/MFMA/barrier counts are
// IDENTICAL to R5 -> isolates schedule depth.

#define DEV __device__ __forceinline__

typedef __attribute__((ext_vector_type(8))) short bf16x8;
typedef __attribute__((ext_vector_type(4))) float f32x4;
typedef unsigned short us;

DEV float bf2f(us u) {
  union { unsigned int i; float f; } v; v.i = ((unsigned int)u) << 16; return v.f;
}
DEV us f2bf(float f) {
  union { float f; unsigned int i; } v; v.f = f;
  unsigned int r = v.i + 0x7FFFu + ((v.i >> 16) & 1u);
  return (us)(r >> 16);
}
DEV void glds16(const us* g, us* l) {
  __builtin_amdgcn_global_load_lds((const __attribute__((address_space(1))) unsigned int*)g,
                                   (__attribute__((address_space(3))) unsigned int*)l, 16, 0, 0);
}

#define MEMFENCE asm volatile("" ::: "memory")
#define BAR do { MEMFENCE; __builtin_amdgcn_s_barrier(); MEMFENCE; } while (0)
#define LGKM0 asm volatile("s_waitcnt lgkmcnt(0)" ::: "memory")

// ---------------- zero ----------------
__global__ void zero_f32(float* p, int n) {
  int i = blockIdx.x * 256 + threadIdx.x;
  if (i < n) p[i] = 0.f;
}

// ---------------- BN stats ----------------
__global__ __launch_bounds__(256) void bn_stats(const float* __restrict__ x,
                                                float* __restrict__ s_sum, float* __restrict__ s_sq) {
  int t = threadIdx.x;
  int c0 = t * 4;
  size_t row0 = (size_t)blockIdx.x * 64;
  float s[4] = {0.f,0.f,0.f,0.f}, q[4] = {0.f,0.f,0.f,0.f};
  for (int r = 0; r < 64; ++r) {
    f32x4 v = *(const f32x4*)&x[(row0 + r) * 1024 + c0];
    #pragma unroll
    for (int i = 0; i < 4; ++i) { float f = v[i]; s[i] += f; q[i] += f * f; }
  }
  #pragma unroll
  for (int i = 0; i < 4; ++i) { atomicAdd(&s_sum[c0 + i], s[i]); atomicAdd(&s_sq[c0 + i], q[i]); }
}

// ---------------- BN finalize + softplus(scale) ----------------
__global__ void bn_finalize(const float* __restrict__ s_sum, const float* __restrict__ s_sq,
                            const float* __restrict__ gamma, const float* __restrict__ beta,
                            const float* __restrict__ scalep,
                            float* __restrict__ bn_a, float* __restrict__ bn_b, float* __restrict__ invs) {
  int c = threadIdx.x;
  float mean = s_sum[c] * (1.0f / 16384.0f);
  float var  = s_sq[c] * (1.0f / 16384.0f) - mean * mean;
  float a = gamma[c] * rsqrtf(var + 1e-5f);
  bn_a[c] = a;
  bn_b[c] = beta[c] - mean * a;
  float sv = scalep[c];
  float sp = (sv > 20.f) ? sv : log1pf(expf(sv));
  invs[c] = 1.0f / sp;
}

// ---------------- xn = BN(x) as bf16 ----------------
__global__ __launch_bounds__(256) void xn_to_bf16(const float* __restrict__ x,
                                                  const float* __restrict__ bn_a, const float* __restrict__ bn_b,
                                                  us* __restrict__ xn) {
  size_t base = ((size_t)blockIdx.x * 256 + threadIdx.x) * 8;
  int c = (int)(base & 1023);
  f32x4 a0 = *(const f32x4*)&x[base];
  f32x4 a1 = *(const f32x4*)&x[base + 4];
  uint4 o; us* uo = (us*)&o;
  #pragma unroll
  for (int i = 0; i < 4; ++i) uo[i] = f2bf(bn_a[c + i] * a0[i] + bn_b[c + i]);
  #pragma unroll
  for (int i = 0; i < 4; ++i) uo[4 + i] = f2bf(bn_a[c + 4 + i] * a1[i] + bn_b[c + 4 + i]);
  *(uint4*)&xn[base] = o;
}

// ---------------- 64x64 transpose f32 -> bf16 ----------------
__global__ __launch_bounds__(256) void transpose_f32_bf16(const float* __restrict__ in,
                                                          us* __restrict__ out, int R, int Cc) {
  __shared__ float tile[64 * 65];
  int tx = blockIdx.x * 64, ty = blockIdx.y * 64;
  int t = threadIdx.x;
  {
    int rr = t >> 4, g = t & 15;
    #pragma unroll
    for (int p = 0; p < 4; ++p) {
      int r = p * 16 + rr;
      f32x4 v = *(const f32x4*)&in[(size_t)(ty + r) * Cc + tx + g * 4];
      #pragma unroll
      for (int i = 0; i < 4; ++i) tile[r * 65 + g * 4 + i] = v[i];
    }
  }
  __syncthreads();
  {
    int rr = t >> 3, g = t & 7;
    #pragma unroll
    for (int p = 0; p < 2; ++p) {
      int nl = p * 32 + rr;
      uint4 v; us* u = (us*)&v;
      #pragma unroll
      for (int j = 0; j < 8; ++j) u[j] = f2bf(tile[(g * 8 + j) * 65 + nl]);
      *(uint4*)&out[(size_t)(tx + nl) * R + ty + g * 8] = v;
    }
  }
}

// ---------------- gemm256: C[M,N] = A_bf16[M,1024] * Bt_bf16[N,1024]^T + bias ----------------
// 256x256 tile, BK=32, 8 waves (wave tile 128x64: wr=wid>>2, wc=wid&3), ring-4 LDS.
// LDS per buffer per matrix: 128 rows x 64 bf16 (8 slots of 16B); LDS row r pair-packs
// global rows r (logical slots 0-3 = k-chunks) and r+128 (slots 4-7); physical slot =
// logical ^ (r&7) -> 2-way bank aliasing (free). Staging: glds16 with pre-swizzled
// per-lane global source, linear wave-uniform LDS dest (2 glds/matrix/tile/thread).
// Per tile: 2 micro-phases {ds_read | stage | barrier | lgkmcnt(0) | 16 MFMA | barrier},
// counted vmcnt(8) publish at tile end (prefetch distance 3 tiles).
template <typename OutT>
__global__ __launch_bounds__(512, 2) void gemm256(const us* __restrict__ A,
                                                  const us* __restrict__ Bt,
                                                  const float* __restrict__ bias,
                                                  OutT* __restrict__ Ca,
                                                  OutT* __restrict__ Cb) {
  constexpr int GK = 1024;
  __shared__ __align__(16) us As[4][128 * 64];   // 64 KB
  __shared__ __align__(16) us Bs[4][128 * 64];   // 64 KB
  int t = threadIdx.x;
  int wid = t >> 6, lane = t & 63;
  int l16 = lane & 15, qd = lane >> 4;
  int nwx = gridDim.x;
  int id = blockIdx.y * nwx + blockIdx.x;
  int nwg = nwx * (int)gridDim.y;              // 512 or 256, always %8==0
  int sw = (id & 7) * (nwg >> 3) + (id >> 3);  // XCD-chunked bijective swizzle
  int n0 = (sw % nwx) * 256, m0 = (sw / nwx) * 256;

  // staging: wave wid's glds g (g=0,1) fills LDS rows [wid*8 + g*64, +8).
  // lane = rr*8 + sl (rr=row-within-8, sl=physical slot). logical slot lg = sl ^ rr
  // (base rows are %8==0). grp = lg>>2 selects row-half (+128), ch = lg&3 the k-chunk.
  int rr = lane >> 3, sl = lane & 7;
  int lg = sl ^ rr;
  int grp = lg >> 2, ch = lg & 3;
  const us* Asrc = A + (size_t)(m0 + wid * 8 + rr + 128 * grp) * GK + ch * 8;
  const us* Bsrc = Bt + (size_t)(n0 + wid * 8 + rr + 128 * grp) * GK + ch * 8;

  int wr = wid >> 2, wc = wid & 3;             // wave tile: rows wr*128, cols wc*64

  f32x4 acc[8][4];
  const f32x4 zero4 = {0.f, 0.f, 0.f, 0.f};
  #pragma unroll
  for (int i = 0; i < 8; ++i)
    #pragma unroll
    for (int j = 0; j < 4; ++j) acc[i][j] = zero4;

  auto STAGE_A = [&](int kt) {
    int b = kt & 3;
    const us* src = Asrc + (size_t)kt * 32;
    us* dst = (us*)&As[0][0] + b * 8192 + (wid * 8) * 64;
    glds16(src, dst);
    glds16(src + (size_t)64 * GK, dst + 64 * 64);
  };
  auto STAGE_B = [&](int kt) {
    int b = kt & 3;
    const us* src = Bsrc + (size_t)kt * 32;
    us* dst = (us*)&Bs[0][0] + b * 8192 + (wid * 8) * 64;
    glds16(src, dst);
    glds16(src + (size_t)64 * GK, dst + 64 * 64);
  };
  // A fragment: row = wr*128 + i*16 + l16 -> LDS row r=i*16+l16 (grp=wr), k-chunk qd.
  auto LDA = [&](bf16x8* d4, int i0, int b) {
    #pragma unroll
    for (int i = 0; i < 4; ++i) {
      int r = (i0 + i) * 16 + l16;
      int ps = (wr * 4 + qd) ^ (r & 7);
      d4[i] = *(const bf16x8*)((const us*)&As[0][0] + b * 8192 + r * 64 + ps * 8);
    }
  };
  // B fragment: row = wc*64 + j*16 + l16 -> grp = row>>7, LDS row = row&127.
  auto LDB = [&](bf16x8* d4, int b) {
    #pragma unroll
    for (int j = 0; j < 4; ++j) {
      int rowb = wc * 64 + j * 16 + l16;
      int grpb = rowb >> 7, rb = rowb & 127;
      int ps = (grpb * 4 + qd) ^ (rb & 7);
      d4[j] = *(const bf16x8*)((const us*)&Bs[0][0] + b * 8192 + rb * 64 + ps * 8);
    }
  };
  auto MM = [&](int i0, bf16x8* a4, bf16x8* b4) {
    __builtin_amdgcn_s_setprio(1);
    #pragma unroll
    for (int i = 0; i < 4; ++i)
      #pragma unroll
      for (int j = 0; j < 4; ++j)
        acc[i0 + i][j] = __builtin_amdgcn_mfma_f32_16x16x32_bf16(a4[i], b4[j], acc[i0 + i][j], 0, 0, 0);
    __builtin_amdgcn_s_setprio(0);
  };

  // tile body: 2 micro-phases; vm = counted publish of tile kt+1 (-1 = none).
  auto TILE = [&](int kt, bool stage, int vm) {
    int buf = kt & 3;
    bf16x8 afl[4], afh[4], bfv[4];
    LDA(afl, 0, buf); LDB(bfv, buf);
    if (stage) STAGE_A(kt + 3);
    BAR; LGKM0; MM(0, afl, bfv); BAR;
    LDA(afh, 4, buf);
    if (stage) STAGE_B(kt + 3);
    BAR; LGKM0; MM(4, afh, bfv);
    if (vm == 8)      asm volatile("s_waitcnt vmcnt(8)" ::: "memory");
    else if (vm == 4) asm volatile("s_waitcnt vmcnt(4)" ::: "memory");
    else if (vm == 0) asm volatile("s_waitcnt vmcnt(0)" ::: "memory");
    BAR;
  };

  // prologue: tiles 0,1,2 staged (12 glds in flight); publish tile 0 (leave 8).
  STAGE_A(-3 + 3); STAGE_B(0);                 // tile 0
  STAGE_A(1 - 3 + 3); STAGE_B(1);              // tile 1  (explicit for clarity)
  STAGE_A(2); STAGE_B(2);                      // tile 2
  asm volatile("s_waitcnt vmcnt(8)" ::: "memory");
  BAR;

  // steady state: compute kt, stage kt+3, publish kt+1 with vmcnt(8).
  for (int kt = 0; kt < 29; ++kt) TILE(kt, true, 8);
  // epilogue peels: publish 30 (vmcnt 4), 31 (vmcnt 0), compute 31.
  TILE(29, false, 4);
  TILE(30, false, 0);
  TILE(31, false, -1);

  OutT* Cp; int col0;
  if (n0 < 1024) { Cp = Ca; col0 = n0; } else { Cp = Cb; col0 = n0 - 1024; }
  #pragma unroll
  for (int i = 0; i < 8; ++i) {
    int row = m0 + wr * 128 + i * 16 + qd * 4;
    #pragma unroll
    for (int j = 0; j < 4; ++j) {
      int fc = n0 + wc * 64 + j * 16 + l16;   // fused bias col
      float bv = bias[fc];
      int col = col0 + wc * 64 + j * 16 + l16;
      #pragma unroll
      for (int r = 0; r < 4; ++r) {
        float val = acc[i][j][r] + bv;
        if constexpr (sizeof(OutT) == 2)
          ((us*)Cp)[(size_t)(row + r) * 1024 + col] = f2bf(val);
        else
          ((float*)Cp)[(size_t)(row + r) * 1024 + col] = val;
      }
    }
  }
}

// ---------------- focus (in-place on 16384x1024 bf16) ----------------
__global__ __launch_bounds__(256) void focus_kernel(us* __restrict__ buf,
                                                    const float* __restrict__ invs) {
  int row = blockIdx.x;
  us* p = buf + (size_t)row * 1024;
  int t = threadIdx.x;
  int c0 = t * 4;
  uint2 v = *(uint2*)&p[c0];
  us* u = (us*)&v;
  float ti[4]; float s2 = 0.f, s6 = 0.f;
  #pragma unroll
  for (int i = 0; i < 4; ++i) {
    float f = bf2f(u[i]);
    f = fmaxf(f, 0.f) + 1e-6f;
    f *= invs[c0 + i];
    ti[i] = f;
    float f2 = f * f;
    s2 += f2; s6 += f2 * f2 * f2;
  }
  #pragma unroll
  for (int off = 32; off > 0; off >>= 1) { s2 += __shfl_down(s2, off); s6 += __shfl_down(s6, off); }
  __shared__ float red[8]; __shared__ float bc;
  int wid = t >> 6, lane = t & 63;
  if (lane == 0) { red[wid] = s2; red[4 + wid] = s6; }
  __syncthreads();
  if (t == 0) {
    float a = red[0] + red[1] + red[2] + red[3];
    float b2 = red[4] + red[5] + red[6] + red[7];
    bc = sqrtf(a / b2);
  }
  __syncthreads();
  float factor = bc;
  #pragma unroll
  for (int i = 0; i < 4; ++i) u[i] = f2bf(ti[i] * ti[i] * ti[i] * factor);
  *(uint2*)&p[c0] = v;
}

// ---------------- attn stats v3: kv = K^T·V via MFMA ----------------
__global__ __launch_bounds__(256) void attn_stats3(const us* __restrict__ kbuf,
                                                   const us* __restrict__ vbuf,
                                                   float* __restrict__ ksum,
                                                   float* __restrict__ kvpart) {
  int cx = blockIdx.x, h = blockIdx.y, b = blockIdx.z, bh = b * 16 + h;
  int t = threadIdx.x, wid = t >> 6, lane = t & 63;
  int l16 = lane & 15, qd = lane >> 4;
  int wm = (wid & 1) * 32, wn = (wid >> 1) * 32;
  __shared__ __align__(16) us kT[64 * 80];
  __shared__ __align__(16) us vT[64 * 80];
  const f32x4 zero4 = {0.f, 0.f, 0.f, 0.f};
  f32x4 acc[2][2];
  #pragma unroll
  for (int i = 0; i < 2; ++i)
    #pragma unroll
    for (int j = 0; j < 2; ++j) acc[i][j] = zero4;
  float ksacc = 0.f;
  int np = (t & 31) * 2, ch0 = (t >> 5) * 8;

  for (int ck = 0; ck < 4; ++ck) {
    __syncthreads();
    size_t base = ((size_t)b * 2048 + cx * 256 + ck * 64 + np) * 1024 + h * 64 + ch0;
    uint4 k0 = *(const uint4*)&kbuf[base];
    uint4 k1 = *(const uint4*)&kbuf[base + 1024];
    uint4 v0 = *(const uint4*)&vbuf[base];
    uint4 v1 = *(const uint4*)&vbuf[base + 1024];
    us* pk0 = (us*)&k0; us* pk1 = (us*)&k1; us* pv0 = (us*)&v0; us* pv1 = (us*)&v1;
    #pragma unroll
    for (int i = 0; i < 8; ++i) {
      unsigned int pk = (unsigned int)pk0[i] | ((unsigned int)pk1[i] << 16);
      unsigned int pv = (unsigned int)pv0[i] | ((unsigned int)pv1[i] << 16);
      *(unsigned int*)&kT[(ch0 + i) * 80 + np] = pk;
      *(unsigned int*)&vT[(ch0 + i) * 80 + np] = pv;
    }
    __syncthreads();
    if (t < 64) {
      #pragma unroll
      for (int g = 0; g < 8; ++g) {
        bf16x8 kk = *(const bf16x8*)&kT[t * 80 + g * 8];
        #pragma unroll
        for (int j = 0; j < 8; ++j) ksacc += bf2f(((us*)&kk)[j]);
      }
    }
    #pragma unroll
    for (int ks = 0; ks < 2; ++ks) {
      bf16x8 af[2], bfr[2];
      #pragma unroll
      for (int i = 0; i < 2; ++i) {
        af[i]  = *(const bf16x8*)&kT[(wm + i * 16 + l16) * 80 + ks * 32 + qd * 8];
        bfr[i] = *(const bf16x8*)&vT[(wn + i * 16 + l16) * 80 + ks * 32 + qd * 8];
      }
      #pragma unroll
      for (int i = 0; i < 2; ++i)
        #pragma unroll
        for (int j = 0; j < 2; ++j)
          acc[i][j] = __builtin_amdgcn_mfma_f32_16x16x32_bf16(af[i], bfr[j], acc[i][j], 0, 0, 0);
    }
  }
  float* pp = kvpart + ((size_t)cx * 128 + bh) * 4096;
  #pragma unroll
  for (int i = 0; i < 2; ++i) {
    int d = wm + i * 16 + qd * 4;
    #pragma unroll
    for (int j = 0; j < 2; ++j) {
      int e = wn + j * 16 + l16;
      #pragma unroll
      for (int r = 0; r < 4; ++r) pp[(d + r) * 64 + e] = acc[i][j][r];
    }
  }
  if (t < 64) atomicAdd(&ksum[bh * 64 + t], ksacc);
}

// ---------------- kv partial reduce -> kvT (bf16, [bh][e][d]) ----------------
__global__ __launch_bounds__(256) void kv_reduce(const float* __restrict__ part, us* __restrict__ kvT) {
  int bh = blockIdx.x;
  int t = threadIdx.x;
  __shared__ float kvl[4096];
  #pragma unroll
  for (int p = 0; p < 16; ++p) {
    int i = p * 256 + t;
    float s = 0.f;
    #pragma unroll
    for (int c = 0; c < 8; ++c) s += part[((size_t)c * 128 + bh) * 4096 + i];
    kvl[i] = s;
  }
  __syncthreads();
  #pragma unroll
  for (int p = 0; p < 2; ++p) {
    int idx = p * 256 + t;
    int e = idx >> 3, d0 = (idx & 7) * 8;
    uint4 o; us* uo = (us*)&o;
    #pragma unroll
    for (int i = 0; i < 8; ++i) uo[i] = f2bf(kvl[(d0 + i) * 64 + e]);
    *(uint4*)&kvT[(size_t)bh * 4096 + e * 64 + d0] = o;
  }
}

// ---------------- attn_o v2: o = (Q·kv)·z + dwc(v) + dwc_b, MFMA, in place over q ----------------
__global__ __launch_bounds__(256) void attn_o2(us* __restrict__ qod,
                                               const us* __restrict__ vbuf,
                                               const float* __restrict__ ksum,
                                               const us* __restrict__ kvT,
                                               const float* __restrict__ dwcw,
                                               const float* __restrict__ dwcb) {
  int nt = blockIdx.x, h = blockIdx.y, b = blockIdx.z, bh = b * 16 + h;
  int t = threadIdx.x, wid = t >> 6, lane = t & 63;
  int l16 = lane & 15, qd = lane >> 4;
  __shared__ __align__(16) us qs[128 * 64];
  __shared__ __align__(16) us bs[64 * 64];
  __shared__ __align__(16) us vs[132 * 64];
  __shared__ float zl[128];
  __shared__ float ksl[64];
  __shared__ float wl[64 * 5];
  __shared__ float bl[64];
  int rS = t >> 3, gS = t & 7;
  size_t qbase = ((size_t)b * 2048 + nt * 128) * 1024 + h * 64;
  #pragma unroll
  for (int p = 0; p < 4; ++p) {
    int r = p * 32 + rS;
    uint4 v = *(const uint4*)&qod[qbase + (size_t)r * 1024 + gS * 8];
    *(uint4*)&qs[r * 64 + ((gS ^ (r & 7)) * 8)] = v;
  }
  #pragma unroll
  for (int p = 0; p < 2; ++p) {
    int r = p * 32 + rS;
    uint4 v = *(const uint4*)&kvT[(size_t)bh * 4096 + r * 64 + gS * 8];
    *(uint4*)&bs[r * 64 + ((gS ^ (r & 7)) * 8)] = v;
  }
  int n0 = nt * 128;
  #pragma unroll
  for (int p = 0; p < 5; ++p) {
    int idx = p * 256 + t;
    if (idx < 1056) {
      int r = idx >> 3, g = idx & 7;
      int n = n0 - 2 + r;
      uint4 v = make_uint4(0, 0, 0, 0);
      if (n >= 0 && n < 2048)
        v = *(const uint4*)&vbuf[((size_t)b * 2048 + n) * 1024 + h * 64 + g * 8];
      *(uint4*)&vs[r * 64 + g * 8] = v;
    }
  }
  if (t < 64) {
    ksl[t] = ksum[bh * 64 + t];
    bl[t] = dwcb[h * 64 + t];
    #pragma unroll
    for (int j = 0; j < 5; ++j) wl[t * 5 + j] = dwcw[(h * 64 + t) * 5 + j];
  }
  __syncthreads();
  if (t < 128) {
    float zs = 0.f;
    #pragma unroll
    for (int g = 0; g < 8; ++g) {
      bf16x8 qv = *(const bf16x8*)&qs[t * 64 + ((g ^ (t & 7)) * 8)];
      #pragma unroll
      for (int j = 0; j < 8; ++j) zs += bf2f(((us*)&qv)[j]) * ksl[g * 8 + j];
    }
    zl[t] = 1.f / (zs + 1e-6f);
  }
  __syncthreads();
  const f32x4 zero4 = {0.f, 0.f, 0.f, 0.f};
  f32x4 acc[2][4];
  #pragma unroll
  for (int i = 0; i < 2; ++i)
    #pragma unroll
    for (int j = 0; j < 4; ++j) acc[i][j] = zero4;
  #pragma unroll
  for (int ks = 0; ks < 2; ++ks) {
    bf16x8 af[2], bfr[4];
    #pragma unroll
    for (int i = 0; i < 2; ++i) {
      int ml = (wid * 2 + i) * 16 + l16;
      af[i] = *(const bf16x8*)&qs[ml * 64 + (((ks * 4 + qd) ^ (ml & 7)) * 8)];
    }
    #pragma unroll
    for (int j = 0; j < 4; ++j) {
      int nl = j * 16 + l16;
      bfr[j] = *(const bf16x8*)&bs[nl * 64 + (((ks * 4 + qd) ^ (nl & 7)) * 8)];
    }
    #pragma unroll
    for (int i = 0; i < 2; ++i)
      #pragma unroll
      for (int j = 0; j < 4; ++j)
        acc[i][j] = __builtin_amdgcn_mfma_f32_16x16x32_bf16(af[i], bfr[j], acc[i][j], 0, 0, 0);
  }
  #pragma unroll
  for (int i = 0; i < 2; ++i) {
    int rl0 = (wid * 2 + i) * 16 + qd * 4;
    #pragma unroll
    for (int j = 0; j < 4; ++j) {
      int e = j * 16 + l16;
      float w0 = wl[e * 5], w1 = wl[e * 5 + 1], w2 = wl[e * 5 + 2], w3 = wl[e * 5 + 3], w4 = wl[e * 5 + 4];
      float vv[8];
      #pragma unroll
      for (int m = 0; m < 8; ++m) vv[m] = bf2f(vs[(rl0 + m) * 64 + e]);
      float bb = bl[e];
      #pragma unroll
      for (int r = 0; r < 4; ++r) {
        float dwc = vv[r] * w0 + vv[r + 1] * w1 + vv[r + 2] * w2 + vv[r + 3] * w3 + vv[r + 4] * w4;
        float o = acc[i][j][r] * zl[rl0 + r] + dwc + bb;
        qod[qbase + (size_t)(rl0 + r) * 1024 + e] = f2bf(o);
      }
    }
  }
}

extern "C" void kernel_launch(void* const* d_in, const int* in_sizes, int n_in,
                              void* d_out, int out_size, void* d_ws, size_t ws_size,
                              hipStream_t stream) {
  const float* x      = (const float*)d_in[0];
  const float* gamma  = (const float*)d_in[1];
  const float* beta   = (const float*)d_in[2];
  const float* Wqkv   = (const float*)d_in[3];
  const float* bqkv   = (const float*)d_in[4];
  const float* scalep = (const float*)d_in[5];
  const float* dwcw   = (const float*)d_in[6];
  const float* dwcb   = (const float*)d_in[7];
  const float* Wproj  = (const float*)d_in[8];
  const float* bproj  = (const float*)d_in[9];
  float* out = (float*)d_out;

  float* wsf = (float*)d_ws;
  float* s_sum  = wsf;                     // 1024
  float* s_sq   = wsf + 1024;              // 1024
  float* ksum   = wsf + 2048;              // 8192
  float* bn_a   = wsf + 10240;             // 1024
  float* bn_b   = wsf + 11264;             // 1024
  float* invs   = wsf + 12288;             // 1024
  float* kvpart = wsf + 13312;             // 8*128*4096 f32
  us* kvT = (us*)(wsf + 4207616);          // 128*4096 bf16
  us* wtq = (us*)(wsf + 4469760);          // 3072x1024 bf16
  us* wtp = (us*)(wsf + 6042624);          // 1024x1024 bf16
  us* kq  = (us*)(wsf + 6566912);          // 16384x1024 bf16: k, then q, then o+dwc
  us* vbf = (us*)d_out;                    // v bf16 in low half of d_out
  us* xnb = (us*)d_out + 16777216;         // xn bf16 in high half of d_out

  zero_f32<<<40, 256, 0, stream>>>(wsf, 10240);
  bn_stats<<<256, 256, 0, stream>>>(x, s_sum, s_sq);
  bn_finalize<<<1, 1024, 0, stream>>>(s_sum, s_sq, gamma, beta, scalep, bn_a, bn_b, invs);
  xn_to_bf16<<<8192, 256, 0, stream>>>(x, bn_a, bn_b, xnb);
  transpose_f32_bf16<<<dim3(48, 16), 256, 0, stream>>>(Wqkv, wtq, 1024, 3072);
  transpose_f32_bf16<<<dim3(16, 16), 256, 0, stream>>>(Wproj, wtp, 1024, 1024);

  // fused k+v: N=2048 (Bt rows 1024..3071 of wtq), n0<1024 -> k (kq), else v (vbf)
  gemm256<us><<<dim3(8, 64), 512, 0, stream>>>(xnb, wtq + 1024 * 1024, bqkv + 1024, kq, vbf);
  focus_kernel<<<16384, 256, 0, stream>>>(kq, invs);                                   // focus(k)
  attn_stats3<<<dim3(8, 16, 8), 256, 0, stream>>>(kq, vbf, ksum, kvpart);
  kv_reduce<<<128, 256, 0, stream>>>(kvpart, kvT);
  gemm256<us><<<dim3(4, 64), 512, 0, stream>>>(xnb, wtq, bqkv, kq, kq);                // q (over k)
  focus_kernel<<<16384, 256, 0, stream>>>(kq, invs);                                   // focus(q)
  attn_o2<<<dim3(16, 16, 8), 256, 0, stream>>>(kq, vbf, ksum, kvT, dwcw, dwcb);        // o + dwc
  gemm256<float><<<dim3(4, 64), 512, 0, stream>>>(kq, wtp, bproj, out, out);           // proj
}

// Round 7
// 387.391 us; speedup vs baseline: 1.1239x; 1.1239x over previous
//
#include <hip/hip_runtime.h>

// MHABlock (f32 I/O): BN -> xn(bf16) -> fused {k,v} + q MFMA GEMMs (8-phase pipelined) ->
// focus(q,k) -> linear attention (kv via MFMA K^T·V; o via MFMA Q·kv with fused dwc) ->
// proj GEMM (f32 out).
//
// R7: gemm256 reverted to R5 (best measured: kv 77.5us, MfmaUtil 36.5; R6's BK=32/
// ring-4/counted-vmcnt regressed to 94us). Non-GEMM de-serialization:
//  - focus_kernel: wave-per-row (4 rows/block, grid 4096, shfl_xor butterfly only;
//    was 16384 one-row blocks with LDS reduce + t==0 serial combine).
//  - transposes merged into one launch.
//  - attn_stats3 ksum: all 256 threads (d x row-quarter) instead of wave0-only.

#define DEV __device__ __forceinline__

typedef __attribute__((ext_vector_type(8))) short bf16x8;
typedef __attribute__((ext_vector_type(4))) float f32x4;
typedef unsigned short us;

DEV float bf2f(us u) {
  union { unsigned int i; float f; } v; v.i = ((unsigned int)u) << 16; return v.f;
}
DEV us f2bf(float f) {
  union { float f; unsigned int i; } v; v.f = f;
  unsigned int r = v.i + 0x7FFFu + ((v.i >> 16) & 1u);
  return (us)(r >> 16);
}
DEV void glds16(const us* g, us* l) {
  __builtin_amdgcn_global_load_lds((const __attribute__((address_space(1))) unsigned int*)g,
                                   (__attribute__((address_space(3))) unsigned int*)l, 16, 0, 0);
}

#define MEMFENCE asm volatile("" ::: "memory")
#define BAR do { MEMFENCE; __builtin_amdgcn_s_barrier(); MEMFENCE; } while (0)
#define LGKM0 asm volatile("s_waitcnt lgkmcnt(0)" ::: "memory")

// ---------------- zero ----------------
__global__ void zero_f32(float* p, int n) {
  int i = blockIdx.x * 256 + threadIdx.x;
  if (i < n) p[i] = 0.f;
}

// ---------------- BN stats ----------------
__global__ __launch_bounds__(256) void bn_stats(const float* __restrict__ x,
                                                float* __restrict__ s_sum, float* __restrict__ s_sq) {
  int t = threadIdx.x;
  int c0 = t * 4;
  size_t row0 = (size_t)blockIdx.x * 64;
  float s[4] = {0.f,0.f,0.f,0.f}, q[4] = {0.f,0.f,0.f,0.f};
  for (int r = 0; r < 64; ++r) {
    f32x4 v = *(const f32x4*)&x[(row0 + r) * 1024 + c0];
    #pragma unroll
    for (int i = 0; i < 4; ++i) { float f = v[i]; s[i] += f; q[i] += f * f; }
  }
  #pragma unroll
  for (int i = 0; i < 4; ++i) { atomicAdd(&s_sum[c0 + i], s[i]); atomicAdd(&s_sq[c0 + i], q[i]); }
}

// ---------------- BN finalize + softplus(scale) ----------------
__global__ void bn_finalize(const float* __restrict__ s_sum, const float* __restrict__ s_sq,
                            const float* __restrict__ gamma, const float* __restrict__ beta,
                            const float* __restrict__ scalep,
                            float* __restrict__ bn_a, float* __restrict__ bn_b, float* __restrict__ invs) {
  int c = threadIdx.x;
  float mean = s_sum[c] * (1.0f / 16384.0f);
  float var  = s_sq[c] * (1.0f / 16384.0f) - mean * mean;
  float a = gamma[c] * rsqrtf(var + 1e-5f);
  bn_a[c] = a;
  bn_b[c] = beta[c] - mean * a;
  float sv = scalep[c];
  float sp = (sv > 20.f) ? sv : log1pf(expf(sv));
  invs[c] = 1.0f / sp;
}

// ---------------- xn = BN(x) as bf16 ----------------
__global__ __launch_bounds__(256) void xn_to_bf16(const float* __restrict__ x,
                                                  const float* __restrict__ bn_a, const float* __restrict__ bn_b,
                                                  us* __restrict__ xn) {
  size_t base = ((size_t)blockIdx.x * 256 + threadIdx.x) * 8;
  int c = (int)(base & 1023);
  f32x4 a0 = *(const f32x4*)&x[base];
  f32x4 a1 = *(const f32x4*)&x[base + 4];
  uint4 o; us* uo = (us*)&o;
  #pragma unroll
  for (int i = 0; i < 4; ++i) uo[i] = f2bf(bn_a[c + i] * a0[i] + bn_b[c + i]);
  #pragma unroll
  for (int i = 0; i < 4; ++i) uo[4 + i] = f2bf(bn_a[c + 4 + i] * a1[i] + bn_b[c + 4 + i]);
  *(uint4*)&xn[base] = o;
}

// ---------------- merged 64x64 transposes f32 -> bf16 (Wqkv | Wproj) ----------------
__global__ __launch_bounds__(256) void transpose2(const float* __restrict__ Wqkv,
                                                  const float* __restrict__ Wproj,
                                                  us* __restrict__ outq, us* __restrict__ outp) {
  __shared__ float tile[64 * 65];
  int bx = blockIdx.x;
  const float* in; us* out; int Cc, tx;
  if (bx < 48) { in = Wqkv;  out = outq; Cc = 3072; tx = bx * 64; }
  else         { in = Wproj; out = outp; Cc = 1024; tx = (bx - 48) * 64; }
  const int R = 1024;
  int ty = blockIdx.y * 64;
  int t = threadIdx.x;
  {
    int rr = t >> 4, g = t & 15;
    #pragma unroll
    for (int p = 0; p < 4; ++p) {
      int r = p * 16 + rr;
      f32x4 v = *(const f32x4*)&in[(size_t)(ty + r) * Cc + tx + g * 4];
      #pragma unroll
      for (int i = 0; i < 4; ++i) tile[r * 65 + g * 4 + i] = v[i];
    }
  }
  __syncthreads();
  {
    int rr = t >> 3, g = t & 7;
    #pragma unroll
    for (int p = 0; p < 2; ++p) {
      int nl = p * 32 + rr;
      uint4 v; us* u = (us*)&v;
      #pragma unroll
      for (int j = 0; j < 8; ++j) u[j] = f2bf(tile[(g * 8 + j) * 65 + nl]);
      *(uint4*)&out[(size_t)(tx + nl) * R + ty + g * 8] = v;
    }
  }
}

// ---------------- gemm256: C[M,N] = A_bf16[M,1024] * Bt_bf16[N,1024]^T + bias ----------------
// (R5 schedule, verbatim.) 256x256 tile, BK=64, 8 waves (wave tile 128x64), ring-2 LDS,
// 8-phase micro-interleave: 4 micro-phases per tile {ds_read subtile | stage-issue |
// barrier | lgkmcnt(0) | setprio(1) 16 MFMA setprio(0) | barrier}; publish tile kt+1
// via vmcnt(0) at q3 (>=3 micro-phases after issue). LDS row = 64 bf16 = 8 slots of
// 16B, physical slot = logical ^ (row&7). glds16 pre-swizzled global source.
template <typename OutT>
__global__ __launch_bounds__(512, 2) void gemm256(const us* __restrict__ A,
                                                  const us* __restrict__ Bt,
                                                  const float* __restrict__ bias,
                                                  OutT* __restrict__ Ca,
                                                  OutT* __restrict__ Cb) {
  constexpr int GK = 1024;
  __shared__ __align__(16) us As[2][2][128 * 64];   // [buf][half][row*64+k]
  __shared__ __align__(16) us Bs[2][2][128 * 64];
  int t = threadIdx.x;
  int wid = t >> 6, lane = t & 63;
  int l16 = lane & 15, qd = lane >> 4;
  int nwx = gridDim.x;
  int id = blockIdx.y * nwx + blockIdx.x;
  int nwg = nwx * (int)gridDim.y;              // 512 or 256, always %8==0
  int sw = (id & 7) * (nwg >> 3) + (id >> 3);  // XCD-chunked bijective swizzle
  int n0 = (sw % nwx) * 256, m0 = (sw / nwx) * 256;

  int rr = lane >> 3, lg = (lane & 7) ^ rr;    // lane's logical k-chunk
  const us* Asrc = A + (size_t)(m0 + wid * 8 + rr) * GK + lg * 8;
  const us* Bsrc = Bt + (size_t)(n0 + wid * 8 + rr) * GK + lg * 8;

  int wr = wid >> 2, wc = wid & 3;             // wave tile: rows wr*128, cols wc*64
  int bh = wc >> 1, brow0 = (wc & 1) * 64;     // B-half + row base within it

  f32x4 acc[8][4];
  const f32x4 zero4 = {0.f, 0.f, 0.f, 0.f};
  #pragma unroll
  for (int i = 0; i < 8; ++i)
    #pragma unroll
    for (int j = 0; j < 4; ++j) acc[i][j] = zero4;

  auto STAGE_A = [&](int kt, int b) {
    const us* src = Asrc + kt * 64;
    us* dst = (us*)&As[b][0][0] + wid * 512;
    #pragma unroll
    for (int g = 0; g < 4; ++g)
      glds16(src + (size_t)(g * 64) * GK, dst + g * 4096);
  };
  auto STAGE_B = [&](int kt, int b) {
    const us* src = Bsrc + kt * 64;
    us* dst = (us*)&Bs[b][0][0] + wid * 512;
    #pragma unroll
    for (int g = 0; g < 4; ++g)
      glds16(src + (size_t)(g * 64) * GK, dst + g * 4096);
  };
  auto LDA = [&](bf16x8* dst, int i0, int ks, int b) {
    #pragma unroll
    for (int i = 0; i < 4; ++i) {
      int r = (i0 + i) * 16 + l16;
      int sl = (ks * 4 + qd) ^ (r & 7);
      dst[i] = *(const bf16x8*)&As[b][wr][r * 64 + sl * 8];
    }
  };
  auto LDB = [&](bf16x8* dst, int ks, int b) {
    #pragma unroll
    for (int j = 0; j < 4; ++j) {
      int r = brow0 + j * 16 + l16;
      int sl = (ks * 4 + qd) ^ (r & 7);
      dst[j] = *(const bf16x8*)&Bs[b][bh][r * 64 + sl * 8];
    }
  };
  auto MM = [&](int i0, bf16x8* a4, bf16x8* b4) {
    __builtin_amdgcn_s_setprio(1);
    #pragma unroll
    for (int i = 0; i < 4; ++i)
      #pragma unroll
      for (int j = 0; j < 4; ++j)
        acc[i0 + i][j] = __builtin_amdgcn_mfma_f32_16x16x32_bf16(a4[i], b4[j], acc[i0 + i][j], 0, 0, 0);
    __builtin_amdgcn_s_setprio(0);
  };

  // prologue: tile 0 staged, drained, published
  STAGE_A(0, 0); STAGE_B(0, 0);
  asm volatile("s_waitcnt vmcnt(0)" ::: "memory");
  BAR;

  for (int kt = 0; kt < 16; ++kt) {
    int buf = kt & 1, nxt = buf ^ 1;
    bf16x8 afl[4], afh[4], bfv[4];
    // ---- q0: read af[0..3]ks0 + bf ks0 | stage A(kt+1) | 16 MFMA
    LDA(afl, 0, 0, buf); LDB(bfv, 0, buf);
    if (kt < 15) STAGE_A(kt + 1, nxt);
    BAR; LGKM0; MM(0, afl, bfv); BAR;
    // ---- q1: read af[4..7]ks0 | stage B(kt+1) | 16 MFMA (bf reused)
    LDA(afh, 4, 0, buf);
    if (kt < 15) STAGE_B(kt + 1, nxt);
    BAR; LGKM0; MM(4, afh, bfv); BAR;
    // ---- q2: read af[0..3]ks1 + bf ks1 | 16 MFMA
    LDA(afl, 0, 1, buf); LDB(bfv, 1, buf);
    BAR; LGKM0; MM(0, afl, bfv); BAR;
    // ---- q3: read af[4..7]ks1 | vmcnt(0) publish kt+1 | 16 MFMA
    LDA(afh, 4, 1, buf);
    asm volatile("s_waitcnt vmcnt(0)" ::: "memory");
    BAR; LGKM0; MM(4, afh, bfv); BAR;
  }

  OutT* Cp; int col0;
  if (n0 < 1024) { Cp = Ca; col0 = n0; } else { Cp = Cb; col0 = n0 - 1024; }
  #pragma unroll
  for (int i = 0; i < 8; ++i) {
    int row = m0 + wr * 128 + i * 16 + qd * 4;
    #pragma unroll
    for (int j = 0; j < 4; ++j) {
      int fc = n0 + wc * 64 + j * 16 + l16;   // fused bias col
      float bv = bias[fc];
      int col = col0 + wc * 64 + j * 16 + l16;
      #pragma unroll
      for (int r = 0; r < 4; ++r) {
        float val = acc[i][j][r] + bv;
        if constexpr (sizeof(OutT) == 2)
          ((us*)Cp)[(size_t)(row + r) * 1024 + col] = f2bf(val);
        else
          ((float*)Cp)[(size_t)(row + r) * 1024 + col] = val;
      }
    }
  }
}

// ---------------- focus: wave-per-row, in-place on 16384x1024 bf16 ----------------
// 4 waves/block = 4 rows/block, grid 4096. Lane owns 16 consecutive channels;
// row-norm via 64-lane shfl_xor butterfly. No LDS, no __syncthreads.
__global__ __launch_bounds__(256) void focus_kernel(us* __restrict__ buf,
                                                    const float* __restrict__ invs) {
  int t = threadIdx.x, wid = t >> 6, lane = t & 63;
  size_t row = (size_t)blockIdx.x * 4 + wid;
  us* p = buf + row * 1024 + lane * 16;
  uint4 v0 = *(uint4*)p;
  uint4 v1 = *(uint4*)(p + 8);
  float ivv[16];
  *(f32x4*)&ivv[0]  = *(const f32x4*)&invs[lane * 16];
  *(f32x4*)&ivv[4]  = *(const f32x4*)&invs[lane * 16 + 4];
  *(f32x4*)&ivv[8]  = *(const f32x4*)&invs[lane * 16 + 8];
  *(f32x4*)&ivv[12] = *(const f32x4*)&invs[lane * 16 + 12];
  us uu[16];
  *(uint4*)&uu[0] = v0; *(uint4*)&uu[8] = v1;
  float f[16];
  float s2 = 0.f, s6 = 0.f;
  #pragma unroll
  for (int i = 0; i < 16; ++i) {
    float x = (fmaxf(bf2f(uu[i]), 0.f) + 1e-6f) * ivv[i];
    f[i] = x;
    float x2 = x * x;
    s2 += x2; s6 += x2 * x2 * x2;
  }
  #pragma unroll
  for (int off = 32; off > 0; off >>= 1) {
    s2 += __shfl_xor(s2, off);
    s6 += __shfl_xor(s6, off);
  }
  float factor = sqrtf(s2 / s6);
  #pragma unroll
  for (int i = 0; i < 16; ++i) uu[i] = f2bf(f[i] * f[i] * f[i] * factor);
  *(uint4*)p = *(uint4*)&uu[0];
  *(uint4*)(p + 8) = *(uint4*)&uu[8];
}

// ---------------- attn stats v3: kv = K^T·V via MFMA ----------------
// grid (8,16,8). ksum now uses all 256 threads: thread = (d = t&63, quarter = t>>6),
// sums 16 rows of channel d per chunk; one atomic per thread at the end.
__global__ __launch_bounds__(256) void attn_stats3(const us* __restrict__ kbuf,
                                                   const us* __restrict__ vbuf,
                                                   float* __restrict__ ksum,
                                                   float* __restrict__ kvpart) {
  int cx = blockIdx.x, h = blockIdx.y, b = blockIdx.z, bh = b * 16 + h;
  int t = threadIdx.x, wid = t >> 6, lane = t & 63;
  int l16 = lane & 15, qd = lane >> 4;
  int wm = (wid & 1) * 32, wn = (wid >> 1) * 32;
  __shared__ __align__(16) us kT[64 * 80];
  __shared__ __align__(16) us vT[64 * 80];
  const f32x4 zero4 = {0.f, 0.f, 0.f, 0.f};
  f32x4 acc[2][2];
  #pragma unroll
  for (int i = 0; i < 2; ++i)
    #pragma unroll
    for (int j = 0; j < 2; ++j) acc[i][j] = zero4;
  float ksacc = 0.f;
  int np = (t & 31) * 2, ch0 = (t >> 5) * 8;
  int kd = t & 63, kq = t >> 6;                // ksum: channel, row-quarter

  for (int ck = 0; ck < 4; ++ck) {
    __syncthreads();
    size_t base = ((size_t)b * 2048 + cx * 256 + ck * 64 + np) * 1024 + h * 64 + ch0;
    uint4 k0 = *(const uint4*)&kbuf[base];
    uint4 k1 = *(const uint4*)&kbuf[base + 1024];
    uint4 v0 = *(const uint4*)&vbuf[base];
    uint4 v1 = *(const uint4*)&vbuf[base + 1024];
    us* pk0 = (us*)&k0; us* pk1 = (us*)&k1; us* pv0 = (us*)&v0; us* pv1 = (us*)&v1;
    #pragma unroll
    for (int i = 0; i < 8; ++i) {
      unsigned int pk = (unsigned int)pk0[i] | ((unsigned int)pk1[i] << 16);
      unsigned int pv = (unsigned int)pv0[i] | ((unsigned int)pv1[i] << 16);
      *(unsigned int*)&kT[(ch0 + i) * 80 + np] = pk;
      *(unsigned int*)&vT[(ch0 + i) * 80 + np] = pv;
    }
    __syncthreads();
    {                                          // ksum: 16 rows of channel kd
      bf16x8 ka = *(const bf16x8*)&kT[kd * 80 + kq * 16];
      bf16x8 kb = *(const bf16x8*)&kT[kd * 80 + kq * 16 + 8];
      #pragma unroll
      for (int j = 0; j < 8; ++j) ksacc += bf2f(((us*)&ka)[j]) + bf2f(((us*)&kb)[j]);
    }
    #pragma unroll
    for (int ks = 0; ks < 2; ++ks) {
      bf16x8 af[2], bfr[2];
      #pragma unroll
      for (int i = 0; i < 2; ++i) {
        af[i]  = *(const bf16x8*)&kT[(wm + i * 16 + l16) * 80 + ks * 32 + qd * 8];
        bfr[i] = *(const bf16x8*)&vT[(wn + i * 16 + l16) * 80 + ks * 32 + qd * 8];
      }
      #pragma unroll
      for (int i = 0; i < 2; ++i)
        #pragma unroll
        for (int j = 0; j < 2; ++j)
          acc[i][j] = __builtin_amdgcn_mfma_f32_16x16x32_bf16(af[i], bfr[j], acc[i][j], 0, 0, 0);
    }
  }
  float* pp = kvpart + ((size_t)cx * 128 + bh) * 4096;
  #pragma unroll
  for (int i = 0; i < 2; ++i) {
    int d = wm + i * 16 + qd * 4;
    #pragma unroll
    for (int j = 0; j < 2; ++j) {
      int e = wn + j * 16 + l16;
      #pragma unroll
      for (int r = 0; r < 4; ++r) pp[(d + r) * 64 + e] = acc[i][j][r];
    }
  }
  atomicAdd(&ksum[bh * 64 + kd], ksacc);
}

// ---------------- kv partial reduce -> kvT (bf16, [bh][e][d]) ----------------
__global__ __launch_bounds__(256) void kv_reduce(const float* __restrict__ part, us* __restrict__ kvT) {
  int bh = blockIdx.x;
  int t = threadIdx.x;
  __shared__ float kvl[4096];
  #pragma unroll
  for (int p = 0; p < 16; ++p) {
    int i = p * 256 + t;
    float s = 0.f;
    #pragma unroll
    for (int c = 0; c < 8; ++c) s += part[((size_t)c * 128 + bh) * 4096 + i];
    kvl[i] = s;
  }
  __syncthreads();
  #pragma unroll
  for (int p = 0; p < 2; ++p) {
    int idx = p * 256 + t;
    int e = idx >> 3, d0 = (idx & 7) * 8;
    uint4 o; us* uo = (us*)&o;
    #pragma unroll
    for (int i = 0; i < 8; ++i) uo[i] = f2bf(kvl[(d0 + i) * 64 + e]);
    *(uint4*)&kvT[(size_t)bh * 4096 + e * 64 + d0] = o;
  }
}

// ---------------- attn_o v2: o = (Q·kv)·z + dwc(v) + dwc_b, MFMA, in place over q ----------------
__global__ __launch_bounds__(256) void attn_o2(us* __restrict__ qod,
                                               const us* __restrict__ vbuf,
                                               const float* __restrict__ ksum,
                                               const us* __restrict__ kvT,
                                               const float* __restrict__ dwcw,
                                               const float* __restrict__ dwcb) {
  int nt = blockIdx.x, h = blockIdx.y, b = blockIdx.z, bh = b * 16 + h;
  int t = threadIdx.x, wid = t >> 6, lane = t & 63;
  int l16 = lane & 15, qd = lane >> 4;
  __shared__ __align__(16) us qs[128 * 64];
  __shared__ __align__(16) us bs[64 * 64];
  __shared__ __align__(16) us vs[132 * 64];
  __shared__ float zl[128];
  __shared__ float ksl[64];
  __shared__ float wl[64 * 5];
  __shared__ float bl[64];
  int rS = t >> 3, gS = t & 7;
  size_t qbase = ((size_t)b * 2048 + nt * 128) * 1024 + h * 64;
  #pragma unroll
  for (int p = 0; p < 4; ++p) {
    int r = p * 32 + rS;
    uint4 v = *(const uint4*)&qod[qbase + (size_t)r * 1024 + gS * 8];
    *(uint4*)&qs[r * 64 + ((gS ^ (r & 7)) * 8)] = v;
  }
  #pragma unroll
  for (int p = 0; p < 2; ++p) {
    int r = p * 32 + rS;
    uint4 v = *(const uint4*)&kvT[(size_t)bh * 4096 + r * 64 + gS * 8];
    *(uint4*)&bs[r * 64 + ((gS ^ (r & 7)) * 8)] = v;
  }
  int n0 = nt * 128;
  #pragma unroll
  for (int p = 0; p < 5; ++p) {
    int idx = p * 256 + t;
    if (idx < 1056) {
      int r = idx >> 3, g = idx & 7;
      int n = n0 - 2 + r;
      uint4 v = make_uint4(0, 0, 0, 0);
      if (n >= 0 && n < 2048)
        v = *(const uint4*)&vbuf[((size_t)b * 2048 + n) * 1024 + h * 64 + g * 8];
      *(uint4*)&vs[r * 64 + g * 8] = v;
    }
  }
  if (t < 64) {
    ksl[t] = ksum[bh * 64 + t];
    bl[t] = dwcb[h * 64 + t];
    #pragma unroll
    for (int j = 0; j < 5; ++j) wl[t * 5 + j] = dwcw[(h * 64 + t) * 5 + j];
  }
  __syncthreads();
  if (t < 128) {
    float zs = 0.f;
    #pragma unroll
    for (int g = 0; g < 8; ++g) {
      bf16x8 qv = *(const bf16x8*)&qs[t * 64 + ((g ^ (t & 7)) * 8)];
      #pragma unroll
      for (int j = 0; j < 8; ++j) zs += bf2f(((us*)&qv)[j]) * ksl[g * 8 + j];
    }
    zl[t] = 1.f / (zs + 1e-6f);
  }
  __syncthreads();
  const f32x4 zero4 = {0.f, 0.f, 0.f, 0.f};
  f32x4 acc[2][4];
  #pragma unroll
  for (int i = 0; i < 2; ++i)
    #pragma unroll
    for (int j = 0; j < 4; ++j) acc[i][j] = zero4;
  #pragma unroll
  for (int ks = 0; ks < 2; ++ks) {
    bf16x8 af[2], bfr[4];
    #pragma unroll
    for (int i = 0; i < 2; ++i) {
      int ml = (wid * 2 + i) * 16 + l16;
      af[i] = *(const bf16x8*)&qs[ml * 64 + (((ks * 4 + qd) ^ (ml & 7)) * 8)];
    }
    #pragma unroll
    for (int j = 0; j < 4; ++j) {
      int nl = j * 16 + l16;
      bfr[j] = *(const bf16x8*)&bs[nl * 64 + (((ks * 4 + qd) ^ (nl & 7)) * 8)];
    }
    #pragma unroll
    for (int i = 0; i < 2; ++i)
      #pragma unroll
      for (int j = 0; j < 4; ++j)
        acc[i][j] = __builtin_amdgcn_mfma_f32_16x16x32_bf16(af[i], bfr[j], acc[i][j], 0, 0, 0);
  }
  #pragma unroll
  for (int i = 0; i < 2; ++i) {
    int rl0 = (wid * 2 + i) * 16 + qd * 4;
    #pragma unroll
    for (int j = 0; j < 4; ++j) {
      int e = j * 16 + l16;
      float w0 = wl[e * 5], w1 = wl[e * 5 + 1], w2 = wl[e * 5 + 2], w3 = wl[e * 5 + 3], w4 = wl[e * 5 + 4];
      float vv[8];
      #pragma unroll
      for (int m = 0; m < 8; ++m) vv[m] = bf2f(vs[(rl0 + m) * 64 + e]);
      float bb = bl[e];
      #pragma unroll
      for (int r = 0; r < 4; ++r) {
        float dwc = vv[r] * w0 + vv[r + 1] * w1 + vv[r + 2] * w2 + vv[r + 3] * w3 + vv[r + 4] * w4;
        float o = acc[i][j][r] * zl[rl0 + r] + dwc + bb;
        qod[qbase + (size_t)(rl0 + r) * 1024 + e] = f2bf(o);
      }
    }
  }
}

extern "C" void kernel_launch(void* const* d_in, const int* in_sizes, int n_in,
                              void* d_out, int out_size, void* d_ws, size_t ws_size,
                              hipStream_t stream) {
  const float* x      = (const float*)d_in[0];
  const float* gamma  = (const float*)d_in[1];
  const float* beta   = (const float*)d_in[2];
  const float* Wqkv   = (const float*)d_in[3];
  const float* bqkv   = (const float*)d_in[4];
  const float* scalep = (const float*)d_in[5];
  const float* dwcw   = (const float*)d_in[6];
  const float* dwcb   = (const float*)d_in[7];
  const float* Wproj  = (const float*)d_in[8];
  const float* bproj  = (const float*)d_in[9];
  float* out = (float*)d_out;

  float* wsf = (float*)d_ws;
  float* s_sum  = wsf;                     // 1024
  float* s_sq   = wsf + 1024;              // 1024
  float* ksum   = wsf + 2048;              // 8192
  float* bn_a   = wsf + 10240;             // 1024
  float* bn_b   = wsf + 11264;             // 1024
  float* invs   = wsf + 12288;             // 1024
  float* kvpart = wsf + 13312;             // 8*128*4096 f32
  us* kvT = (us*)(wsf + 4207616);          // 128*4096 bf16
  us* wtq = (us*)(wsf + 4469760);          // 3072x1024 bf16
  us* wtp = (us*)(wsf + 6042624);          // 1024x1024 bf16
  us* kq  = (us*)(wsf + 6566912);          // 16384x1024 bf16: k, then q, then o+dwc
  us* vbf = (us*)d_out;                    // v bf16 in low half of d_out
  us* xnb = (us*)d_out + 16777216;         // xn bf16 in high half of d_out

  zero_f32<<<40, 256, 0, stream>>>(wsf, 10240);
  bn_stats<<<256, 256, 0, stream>>>(x, s_sum, s_sq);
  bn_finalize<<<1, 1024, 0, stream>>>(s_sum, s_sq, gamma, beta, scalep, bn_a, bn_b, invs);
  xn_to_bf16<<<8192, 256, 0, stream>>>(x, bn_a, bn_b, xnb);
  transpose2<<<dim3(64, 16), 256, 0, stream>>>(Wqkv, Wproj, wtq, wtp);

  // fused k+v: N=2048 (Bt rows 1024..3071 of wtq), n0<1024 -> k (kq), else v (vbf)
  gemm256<us><<<dim3(8, 64), 512, 0, stream>>>(xnb, wtq + 1024 * 1024, bqkv + 1024, kq, vbf);
  focus_kernel<<<4096, 256, 0, stream>>>(kq, invs);                                    // focus(k)
  attn_stats3<<<dim3(8, 16, 8), 256, 0, stream>>>(kq, vbf, ksum, kvpart);
  kv_reduce<<<128, 256, 0, stream>>>(kvpart, kvT);
  gemm256<us><<<dim3(4, 64), 512, 0, stream>>>(xnb, wtq, bqkv, kq, kq);                // q (over k)
  focus_kernel<<<4096, 256, 0, stream>>>(kq, invs);                                    // focus(q)
  attn_o2<<<dim3(16, 16, 8), 256, 0, stream>>>(kq, vbf, ksum, kvT, dwcw, dwcb);        // o + dwc
  gemm256<float><<<dim3(4, 64), 512, 0, stream>>>(kq, wtp, bproj, out, out);           // proj
}